// Round 4
// baseline (476.468 us; speedup 1.0000x reference)
//
#include <hip/hip_runtime.h>
#include <cstdint>
#include <cstddef>

typedef __bf16 bf16_t;
typedef __attribute__((ext_vector_type(4))) __bf16 bf16x4_t;
typedef __attribute__((ext_vector_type(8))) __bf16 bf16x8_t;
typedef __attribute__((ext_vector_type(4))) float f32x4_t;

#define T_TOK   4096
#define IN_DIM  4096
#define OUT_DIM 4096
#define K2      288    // 256 hk cols | 8 w cols | 1 shared_b col | 23 zero pad
#define KSPLIT  8      // gate split-K
#define HSPLIT  4      // svh-gemm split-K (K=1024 each)

#define XSZ ((size_t)T_TOK * IN_DIM)
#define WSZ ((size_t)OUT_DIM * IN_DIM)
#define VSZ ((size_t)256 * IN_DIM)
#define NCAST ((XSZ + WSZ + VSZ) / 1024)   // 33792 cast blocks

__device__ __forceinline__ void gload_lds16(const bf16_t* g, bf16_t* l) {
  __builtin_amdgcn_global_load_lds(
      (__attribute__((address_space(1))) void*)(g),
      (__attribute__((address_space(3))) void*)(l), 16, 0, 0);
}

// ------ casts (x->Xbf, sw->Wbf, svh->Vbf) + tail blocks build B2t ----------
// B2t[o][c] = u[e][o][k] (c=e*32+k) | eb[e][o] (c=256..263) | sb[o] (c=264) | 0
__global__ __launch_bounds__(256) void cast_b2t(const float* __restrict__ x,
                                                const float* __restrict__ sw,
                                                const float* __restrict__ svh,
                                                const float* __restrict__ u,
                                                const float* __restrict__ eb,
                                                const float* __restrict__ sb,
                                                bf16_t* __restrict__ Xbf,
                                                bf16_t* __restrict__ Wbf,
                                                bf16_t* __restrict__ Vbf,
                                                bf16_t* __restrict__ B2t) {
  if (blockIdx.x < NCAST) {
    size_t idx = ((size_t)blockIdx.x * 256 + threadIdx.x) * 4;
    const float* src; bf16_t* dst; size_t i;
    if (idx < XSZ)            { src = x;   dst = Xbf; i = idx; }
    else if (idx < XSZ + WSZ) { src = sw;  dst = Wbf; i = idx - XSZ; }
    else                      { src = svh; dst = Vbf; i = idx - XSZ - WSZ; }
    float4 v = *(const float4*)(src + i);
    bf16x4_t o;
    o[0] = (__bf16)v.x; o[1] = (__bf16)v.y; o[2] = (__bf16)v.z; o[3] = (__bf16)v.w;
    *(bf16x4_t*)(dst + i) = o;
  } else {
    const int o = (int)(blockIdx.x - NCAST);
    for (int c = threadIdx.x; c < K2; c += 256) {
      float v;
      if (c < 256)      v = u[((size_t)(c >> 5) * OUT_DIM + o) * 32 + (c & 31)];
      else if (c < 264) v = eb[(size_t)(c - 256) * OUT_DIM + o];
      else if (c == 264) v = sb[o];
      else              v = 0.f;
      B2t[(size_t)o * K2 + c] = (__bf16)v;
    }
  }
}

// ---------------- fp32 gate matmul, split-K partials (router precision) -----
__global__ __launch_bounds__(256) void gate_partial(const float* __restrict__ x,
                                                    const float* __restrict__ g,
                                                    float* __restrict__ part) {
  __shared__ __align__(16) float Xs[64 * 68];
  __shared__ __align__(16) float Gs[64 * 68];
  const int tid = threadIdx.x;
  const int tbase = blockIdx.x * 64;
  const int kbase = blockIdx.y * (IN_DIM / KSPLIT);
  const int tg = tid & 15;
  const int rg = tid >> 4;
  float acc[4][4] = {{0.f}};

  for (int cc = 0; cc < (IN_DIM / KSPLIT) / 64; ++cc) {
    const int kc = kbase + cc * 64;
    __syncthreads();
#pragma unroll
    for (int j = 0; j < 4; ++j) {
      const int f = tid * 16 + j * 4;
      const int tt = f >> 6, k4 = f & 63;
      float4 xv = *(const float4*)&x[(size_t)(tbase + tt) * IN_DIM + kc + k4];
      Xs[(k4 + 0) * 68 + tt] = xv.x; Xs[(k4 + 1) * 68 + tt] = xv.y;
      Xs[(k4 + 2) * 68 + tt] = xv.z; Xs[(k4 + 3) * 68 + tt] = xv.w;
      float4 gv = *(const float4*)&g[(size_t)tt * IN_DIM + kc + k4];
      Gs[(k4 + 0) * 68 + tt] = gv.x; Gs[(k4 + 1) * 68 + tt] = gv.y;
      Gs[(k4 + 2) * 68 + tt] = gv.z; Gs[(k4 + 3) * 68 + tt] = gv.w;
    }
    __syncthreads();
#pragma unroll 4
    for (int kk = 0; kk < 64; ++kk) {
      float4 xv = *(const float4*)&Xs[kk * 68 + tg * 4];
      float4 gv = *(const float4*)&Gs[kk * 68 + rg * 4];
      float xa[4] = {xv.x, xv.y, xv.z, xv.w};
      float ga[4] = {gv.x, gv.y, gv.z, gv.w};
#pragma unroll
      for (int i = 0; i < 4; ++i)
#pragma unroll
        for (int j = 0; j < 4; ++j) acc[i][j] = fmaf(xa[i], ga[j], acc[i][j]);
    }
  }
#pragma unroll
  for (int i = 0; i < 4; ++i) {
    float4 o4 = make_float4(acc[i][0], acc[i][1], acc[i][2], acc[i][3]);
    *(float4*)&part[((size_t)blockIdx.y * T_TOK + tbase + tg * 4 + i) * 64 + rg * 4] = o4;
  }
}

// ------ svh split-K GEMM: hkp[s][t][n] = sum_{k in s} Xbf[t,k] Vbf[n,k] -----
// grid (2, 32, HSPLIT), 128x128 tile, compile-time dims, K chunk = 1024.
__global__ __launch_bounds__(256) void svh_gemm(const bf16_t* __restrict__ X,
                                                const bf16_t* __restrict__ V,
                                                float* __restrict__ hkp) {
  __shared__ __align__(16) bf16_t As[128 * 32];
  __shared__ __align__(16) bf16_t Bs[128 * 32];
  const int tid = threadIdx.x;
  const int wave = tid >> 6, lane = tid & 63;
  const int mBase = blockIdx.y * 128, nBase = blockIdx.x * 128;
  const int koff = blockIdx.z * (IN_DIM / HSPLIT);
  const int wm = wave >> 1, wn = wave & 1;
  const int lr = lane & 15, lk = (lane >> 4) * 8;
  const int arow = lane >> 2, acol = (lane & 3) * 8;

  f32x4_t acc[4][4];
#pragma unroll
  for (int i = 0; i < 4; ++i)
#pragma unroll
    for (int j = 0; j < 4; ++j) { f32x4_t z = {0.f, 0.f, 0.f, 0.f}; acc[i][j] = z; }

  const bf16_t* gA = X + (size_t)(mBase + wave * 32 + arow) * IN_DIM + koff + acol;
  const bf16_t* gB = V + (size_t)(nBase + wave * 32 + arow) * IN_DIM + koff + acol;
  bf16_t* lA = &As[(wave * 32) * 32];
  bf16_t* lB = &Bs[(wave * 32) * 32];

  for (int k0 = 0; k0 < IN_DIM / HSPLIT; k0 += 32) {
    gload_lds16(gA + k0, lA);
    gload_lds16(gA + k0 + (size_t)16 * IN_DIM, lA + 16 * 32);
    gload_lds16(gB + k0, lB);
    gload_lds16(gB + k0 + (size_t)16 * IN_DIM, lB + 16 * 32);
    __syncthreads();
    bf16x8_t a[4], b[4];
#pragma unroll
    for (int mi = 0; mi < 4; ++mi)
      a[mi] = *(const bf16x8_t*)&As[(wm * 64 + mi * 16 + lr) * 32 + lk];
#pragma unroll
    for (int ni = 0; ni < 4; ++ni)
      b[ni] = *(const bf16x8_t*)&Bs[(wn * 64 + ni * 16 + lr) * 32 + lk];
#pragma unroll
    for (int mi = 0; mi < 4; ++mi)
#pragma unroll
      for (int ni = 0; ni < 4; ++ni)
        acc[mi][ni] = __builtin_amdgcn_mfma_f32_16x16x32_bf16(a[mi], b[ni], acc[mi][ni], 0, 0, 0);
    __syncthreads();
  }

  const int row0 = (lane >> 4) * 4;
  float* hs = hkp + (size_t)blockIdx.z * T_TOK * 256;
#pragma unroll
  for (int mi = 0; mi < 4; ++mi) {
    const int m = mBase + wm * 64 + mi * 16 + row0;
#pragma unroll
    for (int ni = 0; ni < 4; ++ni) {
      const int n = nBase + wn * 64 + ni * 16 + lr;
      f32x4_t v = acc[mi][ni];
#pragma unroll
      for (int r = 0; r < 4; ++r) hs[(size_t)(m + r) * 256 + n] = v[r];
    }
  }
}

// ------ router (fp32 logits -> top2 weights) + A2 build, fused --------------
// A2[t][c] = (sum_s hkp[s][t][c]) * w_{t,c>>5} | w_{t,0..7} | 1.0 | 0pad
__global__ __launch_bounds__(256) void router_a2(const float* __restrict__ part,
                                                 const float* __restrict__ hkp,
                                                 bf16_t* __restrict__ A2) {
  __shared__ float wls[64 * 8];
  const int tid = threadIdx.x;
  const int tbase = blockIdx.x * 64;
  if (tid < 64) {
    const int t = tbase + tid;
    float rl2[8];
#pragma unroll
    for (int e = 0; e < 8; ++e) rl2[e] = 0.f;
#pragma unroll
    for (int r4 = 0; r4 < 16; ++r4) {
      float4 s = make_float4(0.f, 0.f, 0.f, 0.f);
      for (int ks = 0; ks < KSPLIT; ++ks) {
        float4 p = *(const float4*)&part[((size_t)ks * T_TOK + t) * 64 + r4 * 4];
        s.x += p.x; s.y += p.y; s.z += p.z; s.w += p.w;
      }
      rl2[r4 >> 1] += s.x * s.x + s.y * s.y + s.z * s.z + s.w * s.w;
    }
    float rl[8];
#pragma unroll
    for (int e = 0; e < 8; ++e) rl[e] = sqrtf(rl2[e]);
    int e1 = 0; float v1 = rl[0];
#pragma unroll
    for (int e = 1; e < 8; ++e) if (rl[e] > v1) { v1 = rl[e]; e1 = e; }
    int e2 = -1; float v2 = -1e30f;
#pragma unroll
    for (int e = 0; e < 8; ++e) if (e != e1 && rl[e] > v2) { v2 = rl[e]; e2 = e; }
    float w1 = 1.f / (1.f + expf(v2 - v1));
#pragma unroll
    for (int e = 0; e < 8; ++e) wls[tid * 8 + e] = 0.f;
    wls[tid * 8 + e1] = w1; wls[tid * 8 + e2] = 1.f - w1;
  }
  __syncthreads();
  for (int r = 0; r < 64; ++r) {
    const int t = tbase + r;
    for (int c = tid; c < K2; c += 256) {
      float v;
      if (c < 256) {
        float s = hkp[((size_t)0 * T_TOK + t) * 256 + c]
                + hkp[((size_t)1 * T_TOK + t) * 256 + c]
                + hkp[((size_t)2 * T_TOK + t) * 256 + c]
                + hkp[((size_t)3 * T_TOK + t) * 256 + c];
        v = s * wls[r * 8 + (c >> 5)];
      } else if (c < 264) v = wls[r * 8 + (c - 256)];
      else if (c == 264)  v = 1.0f;
      else                v = 0.f;
      A2[(size_t)t * K2 + c] = (__bf16)v;
    }
  }
}

// ------ fused GEMM: out = Xbf.Wbf^T (K=4096) + A2.B2t^T (K=288), pure store -
// 128x128 tile, BK=32, 4 waves 2x2, 16x16x32 MFMA, all dims compile-time.
// Grid 32x32: bx%8 -> XCD round-robin gives each XCD 4 L2-resident B strips.
__global__ __launch_bounds__(256) void gemm_fused(const bf16_t* __restrict__ X,
                                                  const bf16_t* __restrict__ W,
                                                  const bf16_t* __restrict__ A2,
                                                  const bf16_t* __restrict__ B2t,
                                                  float* __restrict__ out) {
  __shared__ __align__(16) bf16_t As[128 * 32];
  __shared__ __align__(16) bf16_t Bs[128 * 32];
  const int tid = threadIdx.x;
  const int wave = tid >> 6, lane = tid & 63;
  const int mBase = blockIdx.y * 128, nBase = blockIdx.x * 128;
  const int wm = wave >> 1, wn = wave & 1;
  const int lr = lane & 15, lk = (lane >> 4) * 8;
  const int arow = lane >> 2, acol = (lane & 3) * 8;

  f32x4_t acc[4][4];
#pragma unroll
  for (int i = 0; i < 4; ++i)
#pragma unroll
    for (int j = 0; j < 4; ++j) { f32x4_t z = {0.f, 0.f, 0.f, 0.f}; acc[i][j] = z; }

  bf16_t* lA = &As[(wave * 32) * 32];
  bf16_t* lB = &Bs[(wave * 32) * 32];

  // ---- phase 1: K = 4096 over X . W^T ----
  {
    const bf16_t* gA = X + (size_t)(mBase + wave * 32 + arow) * IN_DIM + acol;
    const bf16_t* gB = W + (size_t)(nBase + wave * 32 + arow) * IN_DIM + acol;
    for (int k0 = 0; k0 < IN_DIM; k0 += 32) {
      gload_lds16(gA + k0, lA);
      gload_lds16(gA + k0 + (size_t)16 * IN_DIM, lA + 16 * 32);
      gload_lds16(gB + k0, lB);
      gload_lds16(gB + k0 + (size_t)16 * IN_DIM, lB + 16 * 32);
      __syncthreads();
      bf16x8_t a[4], b[4];
#pragma unroll
      for (int mi = 0; mi < 4; ++mi)
        a[mi] = *(const bf16x8_t*)&As[(wm * 64 + mi * 16 + lr) * 32 + lk];
#pragma unroll
      for (int ni = 0; ni < 4; ++ni)
        b[ni] = *(const bf16x8_t*)&Bs[(wn * 64 + ni * 16 + lr) * 32 + lk];
#pragma unroll
      for (int mi = 0; mi < 4; ++mi)
#pragma unroll
        for (int ni = 0; ni < 4; ++ni)
          acc[mi][ni] = __builtin_amdgcn_mfma_f32_16x16x32_bf16(a[mi], b[ni], acc[mi][ni], 0, 0, 0);
      __syncthreads();
    }
  }
  // ---- phase 2: K = 288 tail over A2 . B2t^T (same accumulators) ----
  {
    const bf16_t* gA = A2 + (size_t)(mBase + wave * 32 + arow) * K2 + acol;
    const bf16_t* gB = B2t + (size_t)(nBase + wave * 32 + arow) * K2 + acol;
    for (int k0 = 0; k0 < K2; k0 += 32) {
      gload_lds16(gA + k0, lA);
      gload_lds16(gA + k0 + (size_t)16 * K2, lA + 16 * 32);
      gload_lds16(gB + k0, lB);
      gload_lds16(gB + k0 + (size_t)16 * K2, lB + 16 * 32);
      __syncthreads();
      bf16x8_t a[4], b[4];
#pragma unroll
      for (int mi = 0; mi < 4; ++mi)
        a[mi] = *(const bf16x8_t*)&As[(wm * 64 + mi * 16 + lr) * 32 + lk];
#pragma unroll
      for (int ni = 0; ni < 4; ++ni)
        b[ni] = *(const bf16x8_t*)&Bs[(wn * 64 + ni * 16 + lr) * 32 + lk];
#pragma unroll
      for (int mi = 0; mi < 4; ++mi)
#pragma unroll
        for (int ni = 0; ni < 4; ++ni)
          acc[mi][ni] = __builtin_amdgcn_mfma_f32_16x16x32_bf16(a[mi], b[ni], acc[mi][ni], 0, 0, 0);
      __syncthreads();
    }
  }

  const int row0 = (lane >> 4) * 4;  // C/D: col = lane&15, row = (lane>>4)*4 + r
#pragma unroll
  for (int mi = 0; mi < 4; ++mi) {
    const int m = mBase + wm * 64 + mi * 16 + row0;
#pragma unroll
    for (int ni = 0; ni < 4; ++ni) {
      const int n = nBase + wn * 64 + ni * 16 + lr;
      f32x4_t v = acc[mi][ni];
#pragma unroll
      for (int r = 0; r < 4; ++r) out[(size_t)(m + r) * OUT_DIM + n] = v[r];
    }
  }
}

extern "C" void kernel_launch(void* const* d_in, const int* in_sizes, int n_in,
                              void* d_out, int out_size, void* d_ws, size_t ws_size,
                              hipStream_t stream) {
  const float* x   = (const float*)d_in[0];  // [T, IN]
  const float* gw  = (const float*)d_in[1];  // [64, IN]
  const float* sw  = (const float*)d_in[2];  // [OUT, IN]
  const float* sb  = (const float*)d_in[3];  // [OUT]
  const float* u   = (const float*)d_in[4];  // [E, OUT, 32]
  const float* svh = (const float*)d_in[5];  // [E, 32, IN] == [256, IN]
  const float* eb  = (const float*)d_in[6];  // [E, OUT]
  float* out = (float*)d_out;

  char* ws = (char*)d_ws;
  size_t off = 0;
  auto carve = [&](size_t bytes) {
    void* p = ws + off;
    off = (off + bytes + 255) & ~(size_t)255;
    return p;
  };
  bf16_t* Xbf = (bf16_t*)carve(XSZ * 2);
  bf16_t* Wbf = (bf16_t*)carve(WSZ * 2);
  bf16_t* Vbf = (bf16_t*)carve(VSZ * 2);
  float*  part = (float*)carve((size_t)KSPLIT * T_TOK * 64 * 4);
  float*  hkp  = (float*)carve((size_t)HSPLIT * T_TOK * 256 * 4);
  bf16_t* A2   = (bf16_t*)carve((size_t)T_TOK * K2 * 2);
  bf16_t* B2t  = (bf16_t*)carve((size_t)OUT_DIM * K2 * 2);
  (void)ws_size; (void)in_sizes; (void)n_in; (void)out_size;

  // casts + B2t build (independent of everything downstream)
  cast_b2t<<<(int)(NCAST + OUT_DIM), 256, 0, stream>>>(
      x, sw, svh, u, eb, sb, Xbf, Wbf, Vbf, B2t);

  // fp32 gate (router precision) partials
  gate_partial<<<dim3(T_TOK / 64, KSPLIT), 256, 0, stream>>>(x, gw, part);

  // hk split-K partials (bf16 MFMA)
  svh_gemm<<<dim3(2, 32, HSPLIT), 256, 0, stream>>>(Xbf, Vbf, hkp);

  // router weights + A2 assembly
  router_a2<<<T_TOK / 64, 256, 0, stream>>>(part, hkp, A2);

  // one fused GEMM: pretrained + bias + experts, pure store epilogue
  gemm_fused<<<dim3(OUT_DIM / 128, T_TOK / 128), 256, 0, stream>>>(
      Xbf, Wbf, A2, B2t, out);
}

// Round 5
// 431.242 us; speedup vs baseline: 1.1049x; 1.1049x over previous
//
#include <hip/hip_runtime.h>
#include <cstdint>
#include <cstddef>

typedef __bf16 bf16_t;
typedef __attribute__((ext_vector_type(4))) __bf16 bf16x4_t;
typedef __attribute__((ext_vector_type(8))) __bf16 bf16x8_t;
typedef __attribute__((ext_vector_type(4))) float f32x4_t;

#define T_TOK   4096
#define IN_DIM  4096
#define OUT_DIM 4096
#define K2      288    // 256 hk cols | 8 w cols | 1 shared_b col | 23 zero pad
#define KSPLIT  8      // gate split-K (512 wide)
#define HSPLIT  8      // svh-gemm split-K (K=512 each) -> 512 blocks

#define XSZ ((size_t)T_TOK * IN_DIM)
#define WSZ ((size_t)OUT_DIM * IN_DIM)
#define VSZ ((size_t)256 * IN_DIM)
#define NCAST ((XSZ + WSZ + VSZ) / 1024)     // 33792 cast blocks
#define NGATE (64 * KSPLIT)                  // 512 gate blocks
#define NB2T  OUT_DIM                        // 4096 b2t blocks

__device__ __forceinline__ void gload_lds16(const bf16_t* g, bf16_t* l) {
  __builtin_amdgcn_global_load_lds(
      (__attribute__((address_space(1))) void*)(g),
      (__attribute__((address_space(3))) void*)(l), 16, 0, 0);
}

// ===== K1: uber-kernel — gate partials | B2t build | fp32->bf16 casts ======
// block order: gate (long, LDS-bound) first so it overlaps the cast sea.
__global__ __launch_bounds__(256) void k1_prep(const float* __restrict__ x,
                                               const float* __restrict__ gw,
                                               const float* __restrict__ sw,
                                               const float* __restrict__ svh,
                                               const float* __restrict__ u,
                                               const float* __restrict__ eb,
                                               const float* __restrict__ sb,
                                               bf16_t* __restrict__ Xbf,
                                               bf16_t* __restrict__ Wbf,
                                               bf16_t* __restrict__ Vbf,
                                               bf16_t* __restrict__ B2t,
                                               float* __restrict__ part) {
  __shared__ __align__(16) float GateLds[64 * 68 * 2];  // 34.8 KB (gate only)
  const int bid = blockIdx.x;
  const int tid = threadIdx.x;

  if (bid < NGATE) {
    // ---- fp32 gate matmul partials (router precision) ----
    float* Xs = GateLds;            // [kk][t] stride 68
    float* Gs = GateLds + 64 * 68;  // [kk][r]
    const int tbase = (bid & 63) * 64;
    const int kbase = (bid >> 6) * (IN_DIM / KSPLIT);
    const int tg = tid & 15;
    const int rg = tid >> 4;
    float acc[4][4] = {{0.f}};

    for (int cc = 0; cc < (IN_DIM / KSPLIT) / 64; ++cc) {
      const int kc = kbase + cc * 64;
      __syncthreads();
#pragma unroll
      for (int j = 0; j < 4; ++j) {
        const int f = tid * 16 + j * 4;
        const int tt = f >> 6, k4 = f & 63;
        float4 xv = *(const float4*)&x[(size_t)(tbase + tt) * IN_DIM + kc + k4];
        Xs[(k4 + 0) * 68 + tt] = xv.x; Xs[(k4 + 1) * 68 + tt] = xv.y;
        Xs[(k4 + 2) * 68 + tt] = xv.z; Xs[(k4 + 3) * 68 + tt] = xv.w;
        float4 gv = *(const float4*)&gw[(size_t)tt * IN_DIM + kc + k4];
        Gs[(k4 + 0) * 68 + tt] = gv.x; Gs[(k4 + 1) * 68 + tt] = gv.y;
        Gs[(k4 + 2) * 68 + tt] = gv.z; Gs[(k4 + 3) * 68 + tt] = gv.w;
      }
      __syncthreads();
#pragma unroll 4
      for (int kk = 0; kk < 64; ++kk) {
        float4 xv = *(const float4*)&Xs[kk * 68 + tg * 4];
        float4 gv = *(const float4*)&Gs[kk * 68 + rg * 4];
        float xa[4] = {xv.x, xv.y, xv.z, xv.w};
        float ga[4] = {gv.x, gv.y, gv.z, gv.w};
#pragma unroll
        for (int i = 0; i < 4; ++i)
#pragma unroll
          for (int j = 0; j < 4; ++j) acc[i][j] = fmaf(xa[i], ga[j], acc[i][j]);
      }
    }
    const int ks = bid >> 6;
#pragma unroll
    for (int i = 0; i < 4; ++i) {
      float4 o4 = make_float4(acc[i][0], acc[i][1], acc[i][2], acc[i][3]);
      *(float4*)&part[((size_t)ks * T_TOK + tbase + tg * 4 + i) * 64 + rg * 4] = o4;
    }
  } else if (bid < NGATE + NB2T) {
    // ---- B2t[o][c] = u[e][o][k] | eb[e][o] | sb[o] | 0 ----
    const int o = bid - NGATE;
    for (int c = tid; c < K2; c += 256) {
      float v;
      if (c < 256)       v = u[((size_t)(c >> 5) * OUT_DIM + o) * 32 + (c & 31)];
      else if (c < 264)  v = eb[(size_t)(c - 256) * OUT_DIM + o];
      else if (c == 264) v = sb[o];
      else               v = 0.f;
      B2t[(size_t)o * K2 + c] = (__bf16)v;
    }
  } else {
    // ---- casts: x->Xbf, sw->Wbf, svh->Vbf ----
    size_t idx = ((size_t)(bid - NGATE - NB2T) * 256 + tid) * 4;
    const float* src; bf16_t* dst; size_t i;
    if (idx < XSZ)            { src = x;   dst = Xbf; i = idx; }
    else if (idx < XSZ + WSZ) { src = sw;  dst = Wbf; i = idx - XSZ; }
    else                      { src = svh; dst = Vbf; i = idx - XSZ - WSZ; }
    float4 v = *(const float4*)(src + i);
    bf16x4_t o;
    o[0] = (__bf16)v.x; o[1] = (__bf16)v.y; o[2] = (__bf16)v.z; o[3] = (__bf16)v.w;
    *(bf16x4_t*)(dst + i) = o;
  }
}

// ===== K2: svh split-K GEMM: hkp[s][t][n] = sum_{k in s} Xbf[t,k]Vbf[n,k] ===
// grid (2, 32, HSPLIT) = 512 blocks (2/CU), 128x128 tile, K chunk = 512.
__global__ __launch_bounds__(256) void svh_gemm(const bf16_t* __restrict__ X,
                                                const bf16_t* __restrict__ V,
                                                float* __restrict__ hkp) {
  __shared__ __align__(16) bf16_t As[128 * 32];
  __shared__ __align__(16) bf16_t Bs[128 * 32];
  const int tid = threadIdx.x;
  const int wave = tid >> 6, lane = tid & 63;
  const int mBase = blockIdx.y * 128, nBase = blockIdx.x * 128;
  const int koff = blockIdx.z * (IN_DIM / HSPLIT);
  const int wm = wave >> 1, wn = wave & 1;
  const int lr = lane & 15, lk = (lane >> 4) * 8;
  const int arow = lane >> 2, acol = (lane & 3) * 8;

  f32x4_t acc[4][4];
#pragma unroll
  for (int i = 0; i < 4; ++i)
#pragma unroll
    for (int j = 0; j < 4; ++j) { f32x4_t z = {0.f, 0.f, 0.f, 0.f}; acc[i][j] = z; }

  const bf16_t* gA = X + (size_t)(mBase + wave * 32 + arow) * IN_DIM + koff + acol;
  const bf16_t* gB = V + (size_t)(nBase + wave * 32 + arow) * IN_DIM + koff + acol;
  bf16_t* lA = &As[(wave * 32) * 32];
  bf16_t* lB = &Bs[(wave * 32) * 32];

  for (int k0 = 0; k0 < IN_DIM / HSPLIT; k0 += 32) {
    gload_lds16(gA + k0, lA);
    gload_lds16(gA + k0 + (size_t)16 * IN_DIM, lA + 16 * 32);
    gload_lds16(gB + k0, lB);
    gload_lds16(gB + k0 + (size_t)16 * IN_DIM, lB + 16 * 32);
    __syncthreads();
    bf16x8_t a[4], b[4];
#pragma unroll
    for (int mi = 0; mi < 4; ++mi)
      a[mi] = *(const bf16x8_t*)&As[(wm * 64 + mi * 16 + lr) * 32 + lk];
#pragma unroll
    for (int ni = 0; ni < 4; ++ni)
      b[ni] = *(const bf16x8_t*)&Bs[(wn * 64 + ni * 16 + lr) * 32 + lk];
#pragma unroll
    for (int mi = 0; mi < 4; ++mi)
#pragma unroll
      for (int ni = 0; ni < 4; ++ni)
        acc[mi][ni] = __builtin_amdgcn_mfma_f32_16x16x32_bf16(a[mi], b[ni], acc[mi][ni], 0, 0, 0);
    __syncthreads();
  }

  const int row0 = (lane >> 4) * 4;
  float* hs = hkp + (size_t)blockIdx.z * T_TOK * 256;
#pragma unroll
  for (int mi = 0; mi < 4; ++mi) {
    const int m = mBase + wm * 64 + mi * 16 + row0;
#pragma unroll
    for (int ni = 0; ni < 4; ++ni) {
      const int n = nBase + wn * 64 + ni * 16 + lr;
      f32x4_t v = acc[mi][ni];
#pragma unroll
      for (int r = 0; r < 4; ++r) hs[(size_t)(m + r) * 256 + n] = v[r];
    }
  }
}

// ===== K3: router + A2, wide (256 blocks x 16 tokens, cooperative) ==========
// A2[t][c] = (sum_s hkp[s][t][c]) * w_{t,c>>5} | w_{t,0..7} | 1.0 | 0pad
__global__ __launch_bounds__(256) void router_a2(const float* __restrict__ part,
                                                 const float* __restrict__ hkp,
                                                 bf16_t* __restrict__ A2) {
  __shared__ float pl[16 * 16];   // [token][rquad] partial sum-of-squares
  __shared__ float wls[16 * 8];   // [token][expert] routed weights
  const int tid = threadIdx.x;
  const int tbase = blockIdx.x * 16;

  // phase A: thread (tt, rq) sums 4 r-values over KSPLIT splits, squares
  {
    const int tt = tid >> 4, rq = tid & 15;
    const int t = tbase + tt;
    float4 s = make_float4(0.f, 0.f, 0.f, 0.f);
#pragma unroll
    for (int ks = 0; ks < KSPLIT; ++ks) {
      float4 p = *(const float4*)&part[((size_t)ks * T_TOK + t) * 64 + rq * 4];
      s.x += p.x; s.y += p.y; s.z += p.z; s.w += p.w;
    }
    pl[tt * 16 + rq] = s.x * s.x + s.y * s.y + s.z * s.z + s.w * s.w;
  }
  __syncthreads();
  if (tid < 16) {
    const int tt = tid;
    float rl[8];
#pragma unroll
    for (int e = 0; e < 8; ++e)
      rl[e] = sqrtf(pl[tt * 16 + e * 2] + pl[tt * 16 + e * 2 + 1]);
    int e1 = 0; float v1 = rl[0];
#pragma unroll
    for (int e = 1; e < 8; ++e) if (rl[e] > v1) { v1 = rl[e]; e1 = e; }
    int e2 = -1; float v2 = -1e30f;
#pragma unroll
    for (int e = 0; e < 8; ++e) if (e != e1 && rl[e] > v2) { v2 = rl[e]; e2 = e; }
    float w1 = 1.f / (1.f + expf(v2 - v1));
#pragma unroll
    for (int e = 0; e < 8; ++e) wls[tt * 8 + e] = 0.f;
    wls[tt * 8 + e1] = w1; wls[tt * 8 + e2] = 1.f - w1;
  }
  __syncthreads();
  // phase B: A2 rows for 16 tokens
  for (int tt = 0; tt < 16; ++tt) {
    const int t = tbase + tt;
    for (int c = tid; c < K2; c += 256) {
      float v;
      if (c < 256) {
        float s = 0.f;
#pragma unroll
        for (int ks = 0; ks < HSPLIT; ++ks)
          s += hkp[((size_t)ks * T_TOK + t) * 256 + c];
        v = s * wls[tt * 8 + (c >> 5)];
      } else if (c < 264) v = wls[tt * 8 + (c - 256)];
      else if (c == 264)  v = 1.0f;
      else                v = 0.f;
      A2[(size_t)t * K2 + c] = (__bf16)v;
    }
  }
}

// ===== K4: fused GEMM: out = Xbf.Wbf^T (K=4096) + A2.B2t^T (K=288) =========
// 128x128 tile, BK=32, 4 waves 2x2, 16x16x32 MFMA, compile-time dims,
// grid 32x32 (bx%8 XCD round-robin keeps 4 B-strips L2-resident per XCD).
__global__ __launch_bounds__(256) void gemm_fused(const bf16_t* __restrict__ X,
                                                  const bf16_t* __restrict__ W,
                                                  const bf16_t* __restrict__ A2,
                                                  const bf16_t* __restrict__ B2t,
                                                  float* __restrict__ out) {
  __shared__ __align__(16) bf16_t As[128 * 32];
  __shared__ __align__(16) bf16_t Bs[128 * 32];
  const int tid = threadIdx.x;
  const int wave = tid >> 6, lane = tid & 63;
  const int mBase = blockIdx.y * 128, nBase = blockIdx.x * 128;
  const int wm = wave >> 1, wn = wave & 1;
  const int lr = lane & 15, lk = (lane >> 4) * 8;
  const int arow = lane >> 2, acol = (lane & 3) * 8;

  f32x4_t acc[4][4];
#pragma unroll
  for (int i = 0; i < 4; ++i)
#pragma unroll
    for (int j = 0; j < 4; ++j) { f32x4_t z = {0.f, 0.f, 0.f, 0.f}; acc[i][j] = z; }

  bf16_t* lA = &As[(wave * 32) * 32];
  bf16_t* lB = &Bs[(wave * 32) * 32];

  {  // phase 1: K = 4096 over X . W^T
    const bf16_t* gA = X + (size_t)(mBase + wave * 32 + arow) * IN_DIM + acol;
    const bf16_t* gB = W + (size_t)(nBase + wave * 32 + arow) * IN_DIM + acol;
    for (int k0 = 0; k0 < IN_DIM; k0 += 32) {
      gload_lds16(gA + k0, lA);
      gload_lds16(gA + k0 + (size_t)16 * IN_DIM, lA + 16 * 32);
      gload_lds16(gB + k0, lB);
      gload_lds16(gB + k0 + (size_t)16 * IN_DIM, lB + 16 * 32);
      __syncthreads();
      bf16x8_t a[4], b[4];
#pragma unroll
      for (int mi = 0; mi < 4; ++mi)
        a[mi] = *(const bf16x8_t*)&As[(wm * 64 + mi * 16 + lr) * 32 + lk];
#pragma unroll
      for (int ni = 0; ni < 4; ++ni)
        b[ni] = *(const bf16x8_t*)&Bs[(wn * 64 + ni * 16 + lr) * 32 + lk];
#pragma unroll
      for (int mi = 0; mi < 4; ++mi)
#pragma unroll
        for (int ni = 0; ni < 4; ++ni)
          acc[mi][ni] = __builtin_amdgcn_mfma_f32_16x16x32_bf16(a[mi], b[ni], acc[mi][ni], 0, 0, 0);
      __syncthreads();
    }
  }
  {  // phase 2: K = 288 tail over A2 . B2t^T (same accumulators)
    const bf16_t* gA = A2 + (size_t)(mBase + wave * 32 + arow) * K2 + acol;
    const bf16_t* gB = B2t + (size_t)(nBase + wave * 32 + arow) * K2 + acol;
    for (int k0 = 0; k0 < K2; k0 += 32) {
      gload_lds16(gA + k0, lA);
      gload_lds16(gA + k0 + (size_t)16 * K2, lA + 16 * 32);
      gload_lds16(gB + k0, lB);
      gload_lds16(gB + k0 + (size_t)16 * K2, lB + 16 * 32);
      __syncthreads();
      bf16x8_t a[4], b[4];
#pragma unroll
      for (int mi = 0; mi < 4; ++mi)
        a[mi] = *(const bf16x8_t*)&As[(wm * 64 + mi * 16 + lr) * 32 + lk];
#pragma unroll
      for (int ni = 0; ni < 4; ++ni)
        b[ni] = *(const bf16x8_t*)&Bs[(wn * 64 + ni * 16 + lr) * 32 + lk];
#pragma unroll
      for (int mi = 0; mi < 4; ++mi)
#pragma unroll
        for (int ni = 0; ni < 4; ++ni)
          acc[mi][ni] = __builtin_amdgcn_mfma_f32_16x16x32_bf16(a[mi], b[ni], acc[mi][ni], 0, 0, 0);
      __syncthreads();
    }
  }

  const int row0 = (lane >> 4) * 4;  // C/D: col = lane&15, row = (lane>>4)*4 + r
#pragma unroll
  for (int mi = 0; mi < 4; ++mi) {
    const int m = mBase + wm * 64 + mi * 16 + row0;
#pragma unroll
    for (int ni = 0; ni < 4; ++ni) {
      const int n = nBase + wn * 64 + ni * 16 + lr;
      f32x4_t v = acc[mi][ni];
#pragma unroll
      for (int r = 0; r < 4; ++r) out[(size_t)(m + r) * OUT_DIM + n] = v[r];
    }
  }
}

extern "C" void kernel_launch(void* const* d_in, const int* in_sizes, int n_in,
                              void* d_out, int out_size, void* d_ws, size_t ws_size,
                              hipStream_t stream) {
  const float* x   = (const float*)d_in[0];
  const float* gw  = (const float*)d_in[1];
  const float* sw  = (const float*)d_in[2];
  const float* sb  = (const float*)d_in[3];
  const float* u   = (const float*)d_in[4];
  const float* svh = (const float*)d_in[5];
  const float* eb  = (const float*)d_in[6];
  float* out = (float*)d_out;

  char* ws = (char*)d_ws;
  size_t off = 0;
  auto carve = [&](size_t bytes) {
    void* p = ws + off;
    off = (off + bytes + 255) & ~(size_t)255;
    return p;
  };
  bf16_t* Xbf = (bf16_t*)carve(XSZ * 2);
  bf16_t* Wbf = (bf16_t*)carve(WSZ * 2);
  bf16_t* Vbf = (bf16_t*)carve(VSZ * 2);
  float*  part = (float*)carve((size_t)KSPLIT * T_TOK * 64 * 4);
  float*  hkp  = (float*)carve((size_t)HSPLIT * T_TOK * 256 * 4);
  bf16_t* A2   = (bf16_t*)carve((size_t)T_TOK * K2 * 2);
  bf16_t* B2t  = (bf16_t*)carve((size_t)OUT_DIM * K2 * 2);
  (void)ws_size; (void)in_sizes; (void)n_in; (void)out_size;

  // K1: gate partials + B2t + all casts in one launch
  k1_prep<<<(int)(NGATE + NB2T + NCAST), 256, 0, stream>>>(
      x, gw, sw, svh, u, eb, sb, Xbf, Wbf, Vbf, B2t, part);

  // K2: hk split-K partials (bf16 MFMA), 512 blocks
  svh_gemm<<<dim3(2, 32, HSPLIT), 256, 0, stream>>>(Xbf, Vbf, hkp);

  // K3: router weights + A2 assembly, 256 blocks
  router_a2<<<T_TOK / 16, 256, 0, stream>>>(part, hkp, A2);

  // K4: one fused GEMM -> d_out (pure store epilogue)
  gemm_fused<<<dim3(OUT_DIM / 128, T_TOK / 128), 256, 0, stream>>>(
      Xbf, Wbf, A2, B2t, out);
}